// Round 10
// baseline (178.520 us; speedup 1.0000x reference)
//
#include <hip/hip_runtime.h>

#define N_COLS 24576
#define ROWS 4096
#define KSEL 64
#define TPB 256
#define PRE_F 2.5f      // static prefilter; 64th-largest of a N(0,1) row ≈ 2.79±0.04
#define CAPF 512        // per-row candidate cap (E≈152, σ≈12.3 → 29σ margin)
#define NBINS 2048
#define WAVE_F4 384     // float4 per wave slice (4 waves × 384 = 1536 = row)
#define LANE_F4 6       // float4 per lane (384/64)
#define ROW_F4 6144     // float4 per row

__device__ __forceinline__ unsigned toSortable(float x) {
    unsigned u = __float_as_uint(x);
    return (u & 0x80000000u) ? ~u : (u | 0x80000000u);
}
__device__ __forceinline__ float fromSortable(unsigned s) {
    unsigned u = (s & 0x80000000u) ? (s & 0x7FFFFFFFu) : ~s;
    return __uint_as_float(u);
}

extern "C" __global__ void __launch_bounds__(TPB, 8)
topk_relu_kernel(const float* __restrict__ x, float* __restrict__ out) {
    __shared__ unsigned long long lc[CAPF];    // 4 KB
    __shared__ unsigned hist[NBINS];           // 8 KB (fallback only)
    __shared__ int sh_c, sh_b1, sh_g;

    const int tid  = threadIdx.x;
    const int lane = tid & 63;
    const int wave = tid >> 6;
    const int row  = blockIdx.x;
    const float4* __restrict__ xr = (const float4*)(x + (size_t)row * N_COLS);
    float4* __restrict__ outr     = (float4*)(out + (size_t)row * N_COLS);
    const int base_f4 = wave * WAVE_F4;        // this wave's slice (read AND write)
    // per-row channel-phase rotation: 96 phases × 1 KB, de-convoys the 96KB-
    // strided rows so different rows hit different HBM channels at any instant
    const int rot = (row % 96) * 64;

    if (tid == 0) sh_c = 0;
    __syncthreads();

    const float4 z4 = {0.0f, 0.0f, 0.0f, 0.0f};

    // ---- phase-staggered streaming: even waves W->R, odd waves R->W ----
    auto do_write = [&]() {
        #pragma unroll
        for (int k = 0; k < LANE_F4; ++k) {
            int f4c = base_f4 + k * 64 + lane + rot;
            f4c = (f4c >= ROW_F4) ? f4c - ROW_F4 : f4c;
            outr[f4c] = z4;
        }
    };
    auto do_read = [&]() {
        float4 v[LANE_F4];
        int fc[LANE_F4];
        #pragma unroll
        for (int k = 0; k < LANE_F4; ++k) {         // 6 back-to-back dwordx4 loads
            int f4c = base_f4 + k * 64 + lane + rot;
            f4c = (f4c >= ROW_F4) ? f4c - ROW_F4 : f4c;
            fc[k] = f4c;
            v[k] = xr[f4c];
        }
        #pragma unroll
        for (int k = 0; k < LANE_F4; ++k) {
            if (fmaxf(fmaxf(v[k].x, v[k].y), fmaxf(v[k].z, v[k].w)) > PRE_F) {
                int fb = fc[k] * 4;
                float vv[4] = {v[k].x, v[k].y, v[k].z, v[k].w};
                #pragma unroll
                for (int e = 0; e < 4; ++e) {
                    if (vv[e] > PRE_F) {
                        int p = atomicAdd(&sh_c, 1);
                        if (p < CAPF)
                            lc[p] = ((unsigned long long)toSortable(vv[e]) << 15)
                                  | (unsigned long long)(24575 - (fb + e));
                    }
                }
            }
        }
    };

    if (wave & 1) { do_read(); do_write(); }
    else          { do_write(); do_read(); }

    __syncthreads();   // drains all waves' zero stores (vmcnt) + lc complete

    int C = sh_c;
    if (C >= KSEL && C <= CAPF) {
        // ---- fast exact path: rank-select top-64 among candidates ----
        // Everything excluded by the prefilter is < every candidate, so top-64
        // of candidates == top-64 of the row. Raw u64 compare implements
        // (value desc, index asc) — jax.lax.top_k's tie-break.
        for (int i = tid; i < C; i += TPB) {
            unsigned long long ki = lc[i];
            int rank = 0;
            for (int j = 0; j < C; ++j)
                rank += (lc[j] > ki) ? 1 : 0;      // broadcast LDS reads
            if (rank < KSEL) {
                int idx = 24575 - (int)(ki & 0x7FFFULL);
                float v = fromSortable((unsigned)(ki >> 15));
                out[(size_t)row * N_COLS + idx] = fmaxf(v, 0.0f);
            }
        }
        return;
    }

    // ---- exact histogram fallback (not taken for N(0,1) input, always correct) ----
    for (int i = tid; i < NBINS; i += TPB) hist[i] = 0u;
    if (tid == 0) sh_c = 0;
    __syncthreads();

    for (int j = 0; j < N_COLS / 4 / TPB; ++j) {
        int f = j * TPB + tid;
        float4 v = xr[f];
        atomicAdd(&hist[toSortable(v.x) >> 21], 1u);
        atomicAdd(&hist[toSortable(v.y) >> 21], 1u);
        atomicAdd(&hist[toSortable(v.z) >> 21], 1u);
        atomicAdd(&hist[toSortable(v.w) >> 21], 1u);
    }
    __syncthreads();

    if (tid < 64) {
        unsigned running = 0;
        for (int c = NBINS / 64 - 1; c >= 0; --c) {
            int bin = c * 64 + tid;
            unsigned bc = hist[bin];
            unsigned incl = bc;
            #pragma unroll
            for (int d = 1; d < 64; d <<= 1) {
                unsigned o = __shfl_up(incl, d, 64);
                if (tid >= d) incl += o;
            }
            unsigned total = __shfl(incl, 63, 64);
            unsigned gt = running + (total - incl);
            bool cond = (gt < KSEL) && (gt + bc >= KSEL);
            unsigned long long msk = __ballot(cond);
            if (msk != 0ULL) {
                if (cond) { sh_b1 = bin; sh_g = (int)gt; }
                break;
            }
            running += total;
        }
    }
    __syncthreads();

    const int b1 = sh_b1;
    const int g  = sh_g;

    for (int j = 0; j < N_COLS / 4 / TPB; ++j) {
        int f = j * TPB + tid;
        float4 v = xr[f];
        #define FPROC(comp, e)                                                    \
        {                                                                         \
            unsigned s = toSortable(v.comp);                                      \
            int b = (int)(s >> 21);                                               \
            if (b > b1) {                                                         \
                out[(size_t)row * N_COLS + f * 4 + e] = fmaxf(v.comp, 0.0f);      \
            } else if (b == b1) {                                                 \
                int p = atomicAdd(&sh_c, 1);                                      \
                if (p < CAPF) {                                                   \
                    lc[p] = ((unsigned long long)s << 15) |                       \
                            (unsigned long long)(24575 - (f * 4 + e));            \
                }                                                                 \
            }                                                                     \
        }
        FPROC(x, 0) FPROC(y, 1) FPROC(z, 2) FPROC(w, 3)
        #undef FPROC
    }
    __syncthreads();

    int C2 = sh_c < CAPF ? sh_c : CAPF;
    const int k1 = KSEL - g;
    for (int i = tid; i < C2; i += TPB) {
        unsigned long long ki = lc[i];
        int rank = 0;
        for (int j = 0; j < C2; ++j)
            rank += (lc[j] > ki) ? 1 : 0;
        if (rank < k1) {
            int idx = 24575 - (int)(ki & 0x7FFFULL);
            float v = fromSortable((unsigned)(ki >> 15));
            out[(size_t)row * N_COLS + idx] = fmaxf(v, 0.0f);
        }
    }
}

extern "C" void kernel_launch(void* const* d_in, const int* in_sizes, int n_in,
                              void* d_out, int out_size, void* d_ws, size_t ws_size,
                              hipStream_t stream) {
    const float* x = (const float*)d_in[0];
    float* out = (float*)d_out;
    const int rows = in_sizes[0] / N_COLS;
    topk_relu_kernel<<<rows, TPB, 0, stream>>>(x, out);
}

// Round 11
// 169.009 us; speedup vs baseline: 1.0563x; 1.0563x over previous
//
#include <hip/hip_runtime.h>

#define N_COLS 24576
#define ROWS 4096
#define KSEL 64
#define TPB 256
#define PRE_F 2.5f      // static prefilter; 64th-largest of a N(0,1) row ≈ 2.79±0.04
#define CAPF 512        // per-row candidate cap (E≈152, σ≈12.3 → 29σ margin)
#define NBINS 2048
#define WAVE_F4 384     // float4 per wave slice (4 waves × 384 = 1536 = row)
#define LANE_F4 6       // float4 per lane (384/64)

__device__ __forceinline__ unsigned toSortable(float x) {
    unsigned u = __float_as_uint(x);
    return (u & 0x80000000u) ? ~u : (u | 0x80000000u);
}
__device__ __forceinline__ float fromSortable(unsigned s) {
    unsigned u = (s & 0x80000000u) ? (s & 0x7FFFFFFFu) : ~s;
    return __uint_as_float(u);
}

extern "C" __global__ void __launch_bounds__(TPB, 8)
topk_relu_kernel(const float* __restrict__ x, float* __restrict__ out) {
    __shared__ unsigned long long lc[CAPF];    // 4 KB
    __shared__ unsigned hist[NBINS];           // 8 KB (fallback only)
    __shared__ int sh_c, sh_b1, sh_g;

    const int tid  = threadIdx.x;
    const int lane = tid & 63;
    const int wave = tid >> 6;
    const int row  = blockIdx.x;
    const float4* __restrict__ xr = (const float4*)(x + (size_t)row * N_COLS);
    float4* __restrict__ outr     = (float4*)(out + (size_t)row * N_COLS);
    const int base_f4 = wave * WAVE_F4;        // this wave's slice (read AND write)

    if (tid == 0) sh_c = 0;
    __syncthreads();

    const float4 z4 = {0.0f, 0.0f, 0.0f, 0.0f};

    // ---- staggered + issue-early streaming ----
    // Both wave types issue ALL 12 vmem ops (6 loads + 6 zero-stores) before
    // the first dependent-VALU stall; consume's vmcnt wait covers loads only
    // (stores are younger and keep draining underneath).
    float4 v[LANE_F4];
    auto issue_loads = [&]() {
        #pragma unroll
        for (int k = 0; k < LANE_F4; ++k)      // 6 back-to-back dwordx4 loads
            v[k] = xr[base_f4 + k * 64 + lane];
    };
    auto issue_stores = [&]() {
        #pragma unroll
        for (int k = 0; k < LANE_F4; ++k)      // 6 back-to-back dwordx4 stores
            outr[base_f4 + k * 64 + lane] = z4;
    };

    if (wave & 1) { issue_loads(); issue_stores(); }
    else          { issue_stores(); issue_loads(); }

    // consume: prefilter (first v[k] use triggers the load waits)
    #pragma unroll
    for (int k = 0; k < LANE_F4; ++k) {
        if (fmaxf(fmaxf(v[k].x, v[k].y), fmaxf(v[k].z, v[k].w)) > PRE_F) {
            int fb = (base_f4 + k * 64 + lane) * 4;
            float vv[4] = {v[k].x, v[k].y, v[k].z, v[k].w};
            #pragma unroll
            for (int e = 0; e < 4; ++e) {
                if (vv[e] > PRE_F) {
                    int p = atomicAdd(&sh_c, 1);
                    if (p < CAPF)
                        lc[p] = ((unsigned long long)toSortable(vv[e]) << 15)
                              | (unsigned long long)(24575 - (fb + e));
                }
            }
        }
    }

    __syncthreads();   // drains all waves' zero stores (vmcnt) + lc complete

    int C = sh_c;
    if (C >= KSEL && C <= CAPF) {
        // ---- fast exact path: rank-select top-64 among candidates ----
        // Everything excluded by the prefilter is < every candidate, so top-64
        // of candidates == top-64 of the row. Raw u64 compare implements
        // (value desc, index asc) — jax.lax.top_k's tie-break.
        for (int i = tid; i < C; i += TPB) {
            unsigned long long ki = lc[i];
            int rank = 0;
            for (int j = 0; j < C; ++j)
                rank += (lc[j] > ki) ? 1 : 0;      // broadcast LDS reads
            if (rank < KSEL) {
                int idx = 24575 - (int)(ki & 0x7FFFULL);
                float v2 = fromSortable((unsigned)(ki >> 15));
                out[(size_t)row * N_COLS + idx] = fmaxf(v2, 0.0f);
            }
        }
        return;
    }

    // ---- exact histogram fallback (not taken for N(0,1) input, always correct) ----
    for (int i = tid; i < NBINS; i += TPB) hist[i] = 0u;
    if (tid == 0) sh_c = 0;
    __syncthreads();

    for (int j = 0; j < N_COLS / 4 / TPB; ++j) {
        int f = j * TPB + tid;
        float4 vv = xr[f];
        atomicAdd(&hist[toSortable(vv.x) >> 21], 1u);
        atomicAdd(&hist[toSortable(vv.y) >> 21], 1u);
        atomicAdd(&hist[toSortable(vv.z) >> 21], 1u);
        atomicAdd(&hist[toSortable(vv.w) >> 21], 1u);
    }
    __syncthreads();

    if (tid < 64) {
        unsigned running = 0;
        for (int c = NBINS / 64 - 1; c >= 0; --c) {
            int bin = c * 64 + tid;
            unsigned bc = hist[bin];
            unsigned incl = bc;
            #pragma unroll
            for (int d = 1; d < 64; d <<= 1) {
                unsigned o = __shfl_up(incl, d, 64);
                if (tid >= d) incl += o;
            }
            unsigned total = __shfl(incl, 63, 64);
            unsigned gt = running + (total - incl);
            bool cond = (gt < KSEL) && (gt + bc >= KSEL);
            unsigned long long msk = __ballot(cond);
            if (msk != 0ULL) {
                if (cond) { sh_b1 = bin; sh_g = (int)gt; }
                break;
            }
            running += total;
        }
    }
    __syncthreads();

    const int b1 = sh_b1;
    const int g  = sh_g;

    for (int j = 0; j < N_COLS / 4 / TPB; ++j) {
        int f = j * TPB + tid;
        float4 vv = xr[f];
        #define FPROC(comp, e)                                                    \
        {                                                                         \
            unsigned s = toSortable(vv.comp);                                     \
            int b = (int)(s >> 21);                                               \
            if (b > b1) {                                                         \
                out[(size_t)row * N_COLS + f * 4 + e] = fmaxf(vv.comp, 0.0f);     \
            } else if (b == b1) {                                                 \
                int p = atomicAdd(&sh_c, 1);                                      \
                if (p < CAPF) {                                                   \
                    lc[p] = ((unsigned long long)s << 15) |                       \
                            (unsigned long long)(24575 - (f * 4 + e));            \
                }                                                                 \
            }                                                                     \
        }
        FPROC(x, 0) FPROC(y, 1) FPROC(z, 2) FPROC(w, 3)
        #undef FPROC
    }
    __syncthreads();

    int C2 = sh_c < CAPF ? sh_c : CAPF;
    const int k1 = KSEL - g;
    for (int i = tid; i < C2; i += TPB) {
        unsigned long long ki = lc[i];
        int rank = 0;
        for (int j = 0; j < C2; ++j)
            rank += (lc[j] > ki) ? 1 : 0;
        if (rank < k1) {
            int idx = 24575 - (int)(ki & 0x7FFFULL);
            float v2 = fromSortable((unsigned)(ki >> 15));
            out[(size_t)row * N_COLS + idx] = fmaxf(v2, 0.0f);
        }
    }
}

extern "C" void kernel_launch(void* const* d_in, const int* in_sizes, int n_in,
                              void* d_out, int out_size, void* d_ws, size_t ws_size,
                              hipStream_t stream) {
    const float* x = (const float*)d_in[0];
    float* out = (float*)d_out;
    const int rows = in_sizes[0] / N_COLS;
    topk_relu_kernel<<<rows, TPB, 0, stream>>>(x, out);
}